// Round 1
// baseline (546.002 us; speedup 1.0000x reference)
//
#include <hip/hip_runtime.h>

#define BB 2
#define LL 4096
#define SS 4096
#define HH 8
#define DD 64
#define UU 45
#define SCALE 0.125f

// ---------------------------------------------------------------------------
// K1: M[bh*L + l] = max_u(dot) - sum_u(dot)/S   over 45 sampled keys
// block = 256 threads = 4 waves; each wave handles one l
// ---------------------------------------------------------------------------
__global__ __launch_bounds__(256) void k_compute_M(
    const float* __restrict__ q, const float* __restrict__ k,
    const int* __restrict__ idx, float* __restrict__ M) {
  int wave = threadIdx.x >> 6;
  int lane = threadIdx.x & 63;
  long gw = (long)blockIdx.x * 4 + wave;   // gw = bh*L + l
  int l = (int)(gw & (LL - 1));
  int bh = (int)(gw >> 12);
  int b = bh >> 3, h = bh & 7;
  float qv = q[(((long)b * LL + l) * HH + h) * DD + lane];
  float mx = -INFINITY, sm = 0.f;
  for (int u = 0; u < UU; ++u) {
    int s = idx[l * UU + u];
    float kv = k[(((long)b * SS + s) * HH + h) * DD + lane];
    float p = qv * kv;
    #pragma unroll
    for (int off = 32; off; off >>= 1) p += __shfl_xor(p, off, 64);
    mx = fmaxf(mx, p);
    sm += p;
  }
  if (lane == 0) M[(long)bh * LL + l] = mx - sm * (1.0f / SS);
}

// ---------------------------------------------------------------------------
// K2: top-45 of M per (b,h). Iterative selection, JAX top_k tie-breaking
// (descending value, ties -> lowest index). One block per bh.
// ---------------------------------------------------------------------------
__global__ __launch_bounds__(256) void k_topk(
    const float* __restrict__ M, int* __restrict__ Mtop) {
  __shared__ float vals[LL];
  __shared__ float red_v[256];
  __shared__ int   red_i[256];
  int bh = blockIdx.x;
  const float* m = M + (long)bh * LL;
  for (int i = threadIdx.x; i < LL; i += 256) vals[i] = m[i];
  __syncthreads();
  for (int kk = 0; kk < UU; ++kk) {
    float bv = -INFINITY;
    int bi = 0x7fffffff;
    for (int i = threadIdx.x; i < LL; i += 256) {
      float v = vals[i];
      if (v > bv) { bv = v; bi = i; }   // within-thread: i increasing, strict >
    }
    red_v[threadIdx.x] = bv;
    red_i[threadIdx.x] = bi;
    __syncthreads();
    for (int st = 128; st; st >>= 1) {
      if (threadIdx.x < st) {
        float ov = red_v[threadIdx.x + st];
        int   oi = red_i[threadIdx.x + st];
        if (ov > red_v[threadIdx.x] ||
            (ov == red_v[threadIdx.x] && oi < red_i[threadIdx.x])) {
          red_v[threadIdx.x] = ov;
          red_i[threadIdx.x] = oi;
        }
      }
      __syncthreads();
    }
    if (threadIdx.x == 0) {
      int sel = red_i[0];
      Mtop[bh * UU + kk] = sel;
      vals[sel] = -INFINITY;
    }
    __syncthreads();
  }
}

// ---------------------------------------------------------------------------
// K3: scores[u][s] = (Qr[u] . K[s]) * SCALE for one bh, 256 s per block.
// Q_reduce staged in LDS (broadcast reads), K row in registers.
// ---------------------------------------------------------------------------
__global__ __launch_bounds__(256) void k_scores(
    const float* __restrict__ q, const float* __restrict__ k,
    const int* __restrict__ Mtop, float* __restrict__ attn) {
  __shared__ float qr[UU * DD];
  int bh = blockIdx.y;
  int b = bh >> 3, h = bh & 7;
  for (int i = threadIdx.x; i < UU * DD; i += 256) {
    int u = i >> 6, d = i & 63;
    int l = Mtop[bh * UU + u];
    qr[i] = q[(((long)b * LL + l) * HH + h) * DD + d];
  }
  __syncthreads();
  int s = blockIdx.x * 256 + threadIdx.x;
  float4 kr[16];
  const float4* kp = (const float4*)(k + (((long)b * SS + s) * HH + h) * DD);
  #pragma unroll
  for (int j = 0; j < 16; ++j) kr[j] = kp[j];
  for (int u = 0; u < UU; ++u) {
    const float4* qp = (const float4*)(qr + u * DD);
    float acc = 0.f;
    #pragma unroll
    for (int j = 0; j < 16; ++j) {
      float4 qq = qp[j];
      acc += qq.x * kr[j].x + qq.y * kr[j].y + qq.z * kr[j].z + qq.w * kr[j].w;
    }
    attn[((long)bh * UU + u) * SS + s] = acc * SCALE;
  }
}

// ---------------------------------------------------------------------------
// K4: row softmax over S=4096, one block per row (720 rows), in place.
// ---------------------------------------------------------------------------
__global__ __launch_bounds__(256) void k_softmax(float* __restrict__ attn) {
  __shared__ float red[256];
  long row = blockIdx.x;
  float* a = attn + row * SS;
  float v[16];
  float mx = -INFINITY;
  #pragma unroll
  for (int j = 0; j < 16; ++j) {
    v[j] = a[j * 256 + threadIdx.x];
    mx = fmaxf(mx, v[j]);
  }
  red[threadIdx.x] = mx;
  __syncthreads();
  for (int st = 128; st; st >>= 1) {
    if (threadIdx.x < st) red[threadIdx.x] = fmaxf(red[threadIdx.x], red[threadIdx.x + st]);
    __syncthreads();
  }
  mx = red[0];
  __syncthreads();
  float sm = 0.f;
  #pragma unroll
  for (int j = 0; j < 16; ++j) {
    v[j] = __expf(v[j] - mx);
    sm += v[j];
  }
  red[threadIdx.x] = sm;
  __syncthreads();
  for (int st = 128; st; st >>= 1) {
    if (threadIdx.x < st) red[threadIdx.x] += red[threadIdx.x + st];
    __syncthreads();
  }
  float inv = 1.0f / red[0];
  #pragma unroll
  for (int j = 0; j < 16; ++j) a[j * 256 + threadIdx.x] = v[j] * inv;
}

// ---------------------------------------------------------------------------
// K5: context[row][d] = sum_s attn[row][s] * V[b][s][h][d]; block per row.
// 4 wave-groups of 64 lanes stride s; coalesced 256B V-row loads.
// ---------------------------------------------------------------------------
__global__ __launch_bounds__(256) void k_context(
    const float* __restrict__ attn, const float* __restrict__ v,
    float* __restrict__ ctx) {
  __shared__ float red[4][DD];
  int row = blockIdx.x;            // bh*U + u
  int bh = row / UU;
  int b = bh >> 3, h = bh & 7;
  int lane = threadIdx.x & 63;
  int grp = threadIdx.x >> 6;
  const float* a = attn + (long)row * SS;
  float acc = 0.f;
  for (int s = grp; s < SS; s += 4) {
    acc += a[s] * v[(((long)b * SS + s) * HH + h) * DD + lane];
  }
  red[grp][lane] = acc;
  __syncthreads();
  if (grp == 0) {
    acc = red[0][lane] + red[1][lane] + red[2][lane] + red[3][lane];
    ctx[(long)row * DD + lane] = acc;
  }
}

extern "C" void kernel_launch(void* const* d_in, const int* in_sizes, int n_in,
                              void* d_out, int out_size, void* d_ws, size_t ws_size,
                              hipStream_t stream) {
  const float* q   = (const float*)d_in[0];
  const float* k   = (const float*)d_in[1];
  const float* v   = (const float*)d_in[2];
  const int*   idx = (const int*)d_in[3];

  float* out  = (float*)d_out;
  float* ctx  = out;                          // B*H*U*D = 46080 floats
  float* attn = out + (long)BB * HH * UU * DD; // B*H*U*S floats

  // Scratch overlaid on d_out (write-after-read ordering is safe on stream):
  //  - M (B*H*L floats = 256KB) lives at the start of the attn region;
  //    K3 overwrites it only after K2 consumed it.
  //  - Mtop (720 ints) lives at the start of the ctx region; K5 overwrites
  //    it only after K3 consumed it.
  float* M    = attn;
  int*   Mtop = (int*)ctx;

  k_compute_M<<<BB * HH * LL / 4, 256, 0, stream>>>(q, k, idx, M);
  k_topk<<<BB * HH, 256, 0, stream>>>(M, Mtop);
  k_scores<<<dim3(SS / 256, BB * HH), 256, 0, stream>>>(q, k, Mtop, attn);
  k_softmax<<<BB * HH * UU, 256, 0, stream>>>(attn);
  k_context<<<BB * HH * UU, 256, 0, stream>>>(attn, v, ctx);
}

// Round 2
// 161.666 us; speedup vs baseline: 3.3773x; 3.3773x over previous
//
#include <hip/hip_runtime.h>

#define BB 2
#define LL 4096
#define SS 4096
#define HH 8
#define DD 64
#define UU 45
#define SCALE 0.125f

// ---------------------------------------------------------------------------
// K1: M[bh*L + l] = max_u(dot) - sum_u(dot)/S   over 45 sampled keys.
// 16-lane groups: lane quarter `sub` loads float4 of the row; 4-step
// width-16 shuffle reduce. Block = 256 threads = 16 l-slots.
// idx rows for the block staged in LDS (contiguous, shared across b,h).
// ---------------------------------------------------------------------------
__global__ __launch_bounds__(256) void k_compute_M(
    const float* __restrict__ q, const float* __restrict__ k,
    const int* __restrict__ idx, float* __restrict__ M) {
  __shared__ int sidx[16 * UU];
  int tid = threadIdx.x;
  long glbase = (long)blockIdx.x * 16;
  int l0 = (int)(glbase & (LL - 1));
  for (int i = tid; i < 16 * UU; i += 256) sidx[i] = idx[(long)l0 * UU + i];
  __syncthreads();

  int slot = tid >> 4;    // which l within block
  int sub  = tid & 15;    // d-quarter
  long gl = glbase + slot;       // bh*L + l
  int l  = (int)(gl & (LL - 1));
  int bh = (int)(gl >> 12);
  int b = bh >> 3, h = bh & 7;

  const float4* qp = (const float4*)(q + (((long)b * LL + l) * HH + h) * DD);
  float4 qq = qp[sub];
  const float* kb = k + (long)b * SS * HH * DD + h * DD;

  float mx = -INFINITY, sm = 0.f;
  #pragma unroll 5
  for (int u = 0; u < UU; ++u) {
    int s = sidx[slot * UU + u];
    float4 kk4 = ((const float4*)(kb + (long)s * (HH * DD)))[sub];
    float p = qq.x * kk4.x + qq.y * kk4.y + qq.z * kk4.z + qq.w * kk4.w;
    #pragma unroll
    for (int off = 8; off; off >>= 1) p += __shfl_xor(p, off, 16);
    mx = fmaxf(mx, p);
    sm += p;
  }
  if (sub == 0) M[gl] = mx - sm * (1.0f / SS);
}

// ---------------------------------------------------------------------------
// K2: top-45 per (b,h). Register-local argmax per thread + wave shuffle
// reduce; only the owner thread of the removed element rescans.
// JAX top_k tie rule: descending value, ties -> lowest index.
// ---------------------------------------------------------------------------
__global__ __launch_bounds__(256) void k_topk(
    const float* __restrict__ M, int* __restrict__ Mtop) {
  __shared__ float vals[LL];
  __shared__ float wv[4];
  __shared__ int   wi[4];
  __shared__ int   sel_s;
  int bh = blockIdx.x, tid = threadIdx.x;
  const float* m = M + (long)bh * LL;
  for (int i = tid; i < LL; i += 256) vals[i] = m[i];
  __syncthreads();

  float bv = -INFINITY; int bi = 0x7fffffff;
  #pragma unroll
  for (int j = 0; j < 16; ++j) {
    int i = tid + (j << 8);
    float v2 = vals[i];
    if (v2 > bv) { bv = v2; bi = i; }   // ascending i, strict > => lowest idx
  }
  int lane = tid & 63, w = tid >> 6;

  for (int kk = 0; kk < UU; ++kk) {
    float rv = bv; int ri = bi;
    #pragma unroll
    for (int off = 32; off; off >>= 1) {
      float ov = __shfl_xor(rv, off, 64);
      int   oi = __shfl_xor(ri, off, 64);
      if (ov > rv || (ov == rv && oi < ri)) { rv = ov; ri = oi; }
    }
    if (lane == 0) { wv[w] = rv; wi[w] = ri; }
    __syncthreads();
    if (tid == 0) {
      float fv = wv[0]; int fi = wi[0];
      #pragma unroll
      for (int t = 1; t < 4; ++t)
        if (wv[t] > fv || (wv[t] == fv && wi[t] < fi)) { fv = wv[t]; fi = wi[t]; }
      Mtop[bh * UU + kk] = fi;
      sel_s = fi;
    }
    __syncthreads();
    int sel = sel_s;
    if ((sel & 255) == tid) {           // owner rescans its 16 values
      vals[sel] = -INFINITY;
      bv = -INFINITY; bi = 0x7fffffff;
      #pragma unroll
      for (int j = 0; j < 16; ++j) {
        int i = tid + (j << 8);
        float v2 = vals[i];
        if (v2 > bv) { bv = v2; bi = i; }
      }
    }
  }
}

// ---------------------------------------------------------------------------
// K3: scores[u][s] = (Qr[u] . K[s]) * SCALE for one bh, 256 s per block.
// ---------------------------------------------------------------------------
__global__ __launch_bounds__(256) void k_scores(
    const float* __restrict__ q, const float* __restrict__ k,
    const int* __restrict__ Mtop, float* __restrict__ attn) {
  __shared__ float qr[UU * DD];
  int bh = blockIdx.y;
  int b = bh >> 3, h = bh & 7;
  for (int i = threadIdx.x; i < UU * DD; i += 256) {
    int u = i >> 6, d = i & 63;
    int l = Mtop[bh * UU + u];
    qr[i] = q[(((long)b * LL + l) * HH + h) * DD + d];
  }
  __syncthreads();
  int s = blockIdx.x * 256 + threadIdx.x;
  float4 kr[16];
  const float4* kp = (const float4*)(k + (((long)b * SS + s) * HH + h) * DD);
  #pragma unroll
  for (int j = 0; j < 16; ++j) kr[j] = kp[j];
  for (int u = 0; u < UU; ++u) {
    const float4* qp = (const float4*)(qr + u * DD);
    float acc = 0.f;
    #pragma unroll
    for (int j = 0; j < 16; ++j) {
      float4 qq = qp[j];
      acc += qq.x * kr[j].x + qq.y * kr[j].y + qq.z * kr[j].z + qq.w * kr[j].w;
    }
    attn[((long)bh * UU + u) * SS + s] = acc * SCALE;
  }
}

// ---------------------------------------------------------------------------
// K4: row softmax over S=4096, one block per row (720 rows), in place.
// ---------------------------------------------------------------------------
__global__ __launch_bounds__(256) void k_softmax(float* __restrict__ attn) {
  __shared__ float red[256];
  long row = blockIdx.x;
  float* a = attn + row * SS;
  float v[16];
  float mx = -INFINITY;
  #pragma unroll
  for (int j = 0; j < 16; ++j) {
    v[j] = a[j * 256 + threadIdx.x];
    mx = fmaxf(mx, v[j]);
  }
  red[threadIdx.x] = mx;
  __syncthreads();
  for (int st = 128; st; st >>= 1) {
    if (threadIdx.x < st) red[threadIdx.x] = fmaxf(red[threadIdx.x], red[threadIdx.x + st]);
    __syncthreads();
  }
  mx = red[0];
  __syncthreads();
  float sm = 0.f;
  #pragma unroll
  for (int j = 0; j < 16; ++j) {
    v[j] = __expf(v[j] - mx);
    sm += v[j];
  }
  red[threadIdx.x] = sm;
  __syncthreads();
  for (int st = 128; st; st >>= 1) {
    if (threadIdx.x < st) red[threadIdx.x] += red[threadIdx.x + st];
    __syncthreads();
  }
  float inv = 1.0f / red[0];
  #pragma unroll
  for (int j = 0; j < 16; ++j) a[j * 256 + threadIdx.x] = v[j] * inv;
}

// ---------------------------------------------------------------------------
// K5a: chunked context partials. grid = (nch, B*H); block = 256 (4 waves).
// Each block handles chunk = S/nch s-values for one bh. All 45 u-accumulators
// live in registers (lane = d). attn chunk staged TRANSPOSED in LDS
// (aT[s][u], row stride 52 floats -> aligned b128 broadcast reads).
// V and attn each read exactly once from HBM. Partials -> ws.
// ---------------------------------------------------------------------------
__global__ __launch_bounds__(256) void k_context_part(
    const float* __restrict__ attn, const float* __restrict__ v,
    float* __restrict__ part, int nch) {
  __shared__ float smem[4 * UU * DD];   // 11520 floats; staging uses 128*52=6656
  int ch = blockIdx.x, bh = blockIdx.y;
  int b = bh >> 3, h = bh & 7;
  int tid = threadIdx.x;
  int ln = tid & 63, w = tid >> 6;
  int chunk = SS / nch;
  int s0 = ch * chunk;
  int nsub = chunk >> 7;                // 128-s sub-tiles

  float acc[UU];
  #pragma unroll
  for (int u = 0; u < UU; ++u) acc[u] = 0.f;

  const float* vb = v + (long)b * SS * HH * DD + h * DD + ln;

  for (int sub = 0; sub < nsub; ++sub) {
    int sb = s0 + (sub << 7);
    __syncthreads();                    // protect previous sub-tile reads
    for (int i = tid; i < UU * 128; i += 256) {
      int u = i >> 7, si = i & 127;
      smem[si * 52 + u] = attn[((long)bh * UU + u) * SS + sb + si];
    }
    __syncthreads();
    #pragma unroll 2
    for (int j = 0; j < 32; ++j) {
      int sl = (j << 2) + w;            // 4 waves cover 128 s
      float vd = vb[(long)(sb + sl) * (HH * DD)];
      const float* ar = smem + sl * 52;
      #pragma unroll
      for (int g = 0; g < 11; ++g) {
        float4 aa = *(const float4*)(ar + g * 4);
        acc[g * 4 + 0] += aa.x * vd;
        acc[g * 4 + 1] += aa.y * vd;
        acc[g * 4 + 2] += aa.z * vd;
        acc[g * 4 + 3] += aa.w * vd;
      }
      acc[44] += ar[44] * vd;
    }
  }

  // block-level combine: 4 wave partials -> one
  __syncthreads();
  #pragma unroll
  for (int u = 0; u < UU; ++u) smem[(w * UU + u) * DD + ln] = acc[u];
  __syncthreads();
  long base = ((long)bh * nch + ch) * (UU * DD);
  for (int i = tid; i < UU * DD; i += 256)
    part[base + i] = smem[i] + smem[UU * DD + i] + smem[2 * UU * DD + i] + smem[3 * UU * DD + i];
}

// K5b: sum partials over chunks. 46080 outputs.
__global__ __launch_bounds__(256) void k_context_reduce(
    const float* __restrict__ part, float* __restrict__ ctx, int nch) {
  int g = blockIdx.x * 256 + threadIdx.x;     // < B*H*U*D = 46080
  int bh = g / (UU * DD);
  int r  = g - bh * (UU * DD);
  float s = 0.f;
  for (int ch = 0; ch < nch; ++ch)
    s += part[((long)bh * nch + ch) * (UU * DD) + r];
  ctx[g] = s;
}

// Fallback (old row-per-block context) if d_ws is too small.
__global__ __launch_bounds__(256) void k_context_fb(
    const float* __restrict__ attn, const float* __restrict__ v,
    float* __restrict__ ctx) {
  __shared__ float red[4][DD];
  int row = blockIdx.x;
  int bh = row / UU;
  int b = bh >> 3, h = bh & 7;
  int lane = threadIdx.x & 63;
  int grp = threadIdx.x >> 6;
  const float* a = attn + (long)row * SS;
  float acc = 0.f;
  for (int s = grp; s < SS; s += 4)
    acc += a[s] * v[(((long)b * SS + s) * HH + h) * DD + lane];
  red[grp][lane] = acc;
  __syncthreads();
  if (grp == 0)
    ctx[(long)row * DD + lane] = red[0][lane] + red[1][lane] + red[2][lane] + red[3][lane];
}

extern "C" void kernel_launch(void* const* d_in, const int* in_sizes, int n_in,
                              void* d_out, int out_size, void* d_ws, size_t ws_size,
                              hipStream_t stream) {
  const float* q   = (const float*)d_in[0];
  const float* k   = (const float*)d_in[1];
  const float* v   = (const float*)d_in[2];
  const int*   idx = (const int*)d_in[3];

  float* out  = (float*)d_out;
  float* ctx  = out;                           // B*H*U*D = 46080 floats
  float* attn = out + (long)BB * HH * UU * DD; // B*H*U*S floats

  // Scratch overlays on d_out (safe via stream ordering):
  //  - M lives at start of attn region (consumed by K2 before K3 overwrites)
  //  - Mtop lives at start of ctx region (consumed by K3 before K5 overwrites)
  float* M    = attn;
  int*   Mtop = (int*)ctx;

  k_compute_M<<<BB * HH * LL / 16, 256, 0, stream>>>(q, k, idx, M);
  k_topk<<<BB * HH, 256, 0, stream>>>(M, Mtop);
  k_scores<<<dim3(SS / 256, BB * HH), 256, 0, stream>>>(q, k, Mtop, attn);
  k_softmax<<<BB * HH * UU, 256, 0, stream>>>(attn);

  size_t per_chunk = (size_t)BB * HH * UU * DD * sizeof(float);  // 184320 B
  int nch = 0;
  for (int c = 32; c >= 1; c >>= 1)
    if (ws_size >= per_chunk * (size_t)c) { nch = c; break; }
  if (nch) {
    k_context_part<<<dim3(nch, BB * HH), 256, 0, stream>>>(attn, v, (float*)d_ws, nch);
    k_context_reduce<<<(BB * HH * UU * DD) / 256, 256, 0, stream>>>((const float*)d_ws, ctx, nch);
  } else {
    k_context_fb<<<BB * HH * UU, 256, 0, stream>>>(attn, v, ctx);
  }
}

// Round 3
// 126.839 us; speedup vs baseline: 4.3047x; 1.2746x over previous
//
#include <hip/hip_runtime.h>

#define BB 2
#define LL 4096
#define SS 4096
#define HH 8
#define DD 64
#define UU 45
#define SCALE 0.125f

// ---------------------------------------------------------------------------
// K1: M[bh*L + l] = max_u(dot) - sum_u(dot)/S   over 45 sampled keys.
// 16-lane groups: lane quarter `sub` loads float4 of the row; 4-step
// width-16 shuffle reduce. Block = 256 threads = 16 l-slots.
// ---------------------------------------------------------------------------
__global__ __launch_bounds__(256) void k_compute_M(
    const float* __restrict__ q, const float* __restrict__ k,
    const int* __restrict__ idx, float* __restrict__ M) {
  __shared__ int sidx[16 * UU];
  int tid = threadIdx.x;
  long glbase = (long)blockIdx.x * 16;
  int l0 = (int)(glbase & (LL - 1));
  for (int i = tid; i < 16 * UU; i += 256) sidx[i] = idx[(long)l0 * UU + i];
  __syncthreads();

  int slot = tid >> 4;    // which l within block
  int sub  = tid & 15;    // d-quarter
  long gl = glbase + slot;       // bh*L + l
  int l  = (int)(gl & (LL - 1));
  int bh = (int)(gl >> 12);
  int b = bh >> 3, h = bh & 7;

  const float4* qp = (const float4*)(q + (((long)b * LL + l) * HH + h) * DD);
  float4 qq = qp[sub];
  const float* kb = k + (long)b * SS * HH * DD + h * DD;

  float mx = -INFINITY, sm = 0.f;
  #pragma unroll 5
  for (int u = 0; u < UU; ++u) {
    int s = sidx[slot * UU + u];
    float4 kk4 = ((const float4*)(kb + (long)s * (HH * DD)))[sub];
    float p = qq.x * kk4.x + qq.y * kk4.y + qq.z * kk4.z + qq.w * kk4.w;
    #pragma unroll
    for (int off = 8; off; off >>= 1) p += __shfl_xor(p, off, 16);
    mx = fmaxf(mx, p);
    sm += p;
  }
  if (sub == 0) M[gl] = mx - sm * (1.0f / SS);
}

// ---------------------------------------------------------------------------
// K2: top-45 per (b,h) via 4-pass radix-select on orderable uint32 keys,
// then rank-based emit. Matches jax.lax.top_k: value desc, ties -> lowest
// index. One block (256 thr) per bh; ~5 streaming passes over 4096 LDS words.
// ---------------------------------------------------------------------------
__global__ __launch_bounds__(256) void k_topk(
    const float* __restrict__ M, int* __restrict__ Mtop) {
  __shared__ unsigned keys[LL];        // 16 KB orderable keys
  __shared__ int hist[256];
  __shared__ int wsum[4];
  __shared__ int sh_bin, sh_gtwin;
  __shared__ int ccount, ecount;
  __shared__ unsigned cand_key[64];
  __shared__ int cand_idx[64];
  __shared__ int elist[LL];            // ==T indices (worst-case capacity)

  int bh = blockIdx.x, tid = threadIdx.x;
  int lane = tid & 63, w = tid >> 6;
  const float* m = M + (long)bh * LL;
  for (int i = tid; i < LL; i += 256) {
    union { float f; unsigned u; } cv; cv.f = m[i];
    keys[i] = (cv.u & 0x80000000u) ? ~cv.u : (cv.u | 0x80000000u);
  }
  if (tid == 0) { ccount = 0; ecount = 0; }
  __syncthreads();

  unsigned prefix = 0, pmask = 0;
  int need = UU, above = 0;

  for (int shift = 24; shift >= 0; shift -= 8) {
    hist[tid] = 0;
    __syncthreads();
    #pragma unroll
    for (int j = 0; j < 16; ++j) {
      unsigned kk = keys[tid + (j << 8)];
      if ((kk & pmask) == prefix) atomicAdd(&hist[(kk >> shift) & 255], 1);
    }
    __syncthreads();
    // suffix sum over 256 bins: intra-wave shuffle + cross-wave offsets
    int v = hist[tid];
    int sfx = v;
    #pragma unroll
    for (int st = 1; st < 64; st <<= 1) {
      int o = __shfl_down(sfx, st, 64);
      if (lane + st < 64) sfx += o;
    }
    if (lane == 0) wsum[w] = sfx;      // wave-segment total (suffix from lane0)
    __syncthreads();
    for (int t = w + 1; t < 4; ++t) sfx += wsum[t];
    int gt = sfx - v;                   // keys in bins strictly above tid
    if (gt < need && sfx >= need) {     // exactly one bin satisfies
      sh_bin = tid;
      sh_gtwin = gt;
    }
    __syncthreads();
    prefix |= ((unsigned)sh_bin << shift);
    pmask  |= (255u << shift);
    need  -= sh_gtwin;
    above += sh_gtwin;
    __syncthreads();                    // sh_bin/sh_gtwin consumed before reuse
  }
  unsigned T = prefix;                  // exact 45th-largest key

  #pragma unroll
  for (int j = 0; j < 16; ++j) {
    int i = tid + (j << 8);
    unsigned kk = keys[i];
    if (kk > T)      { int p = atomicAdd(&ccount, 1); cand_key[p] = kk; cand_idx[p] = i; }
    else if (kk == T){ int p = atomicAdd(&ecount, 1); elist[p] = i; }
  }
  __syncthreads();
  int nc = ccount, ne = ecount;
  // rank the >T candidates (nc < 45): value desc, index asc
  for (int t = tid; t < nc; t += 256) {
    unsigned kk = cand_key[t]; int ii = cand_idx[t]; int r = 0;
    for (int j = 0; j < nc; ++j)
      r += (cand_key[j] > kk) || (cand_key[j] == kk && cand_idx[j] < ii);
    Mtop[bh * UU + r] = ii;
  }
  // ==T keys fill ranks [above, 44] in ascending-index order
  for (int t = tid; t < ne; t += 256) {
    int ii = elist[t]; int r = 0;
    for (int j = 0; j < ne; ++j) r += (elist[j] < ii);
    if (r < need) Mtop[bh * UU + above + r] = ii;
  }
}

// ---------------------------------------------------------------------------
// K3: scores[u][s] = (Qr[u] . K[s]) * SCALE for one bh, 256 s per block.
// ---------------------------------------------------------------------------
__global__ __launch_bounds__(256) void k_scores(
    const float* __restrict__ q, const float* __restrict__ k,
    const int* __restrict__ Mtop, float* __restrict__ attn) {
  __shared__ float qr[UU * DD];
  int bh = blockIdx.y;
  int b = bh >> 3, h = bh & 7;
  for (int i = threadIdx.x; i < UU * DD; i += 256) {
    int u = i >> 6, d = i & 63;
    int l = Mtop[bh * UU + u];
    qr[i] = q[(((long)b * LL + l) * HH + h) * DD + d];
  }
  __syncthreads();
  int s = blockIdx.x * 256 + threadIdx.x;
  float4 kr[16];
  const float4* kp = (const float4*)(k + (((long)b * SS + s) * HH + h) * DD);
  #pragma unroll
  for (int j = 0; j < 16; ++j) kr[j] = kp[j];
  for (int u = 0; u < UU; ++u) {
    const float4* qp = (const float4*)(qr + u * DD);
    float acc = 0.f;
    #pragma unroll
    for (int j = 0; j < 16; ++j) {
      float4 qq = qp[j];
      acc += qq.x * kr[j].x + qq.y * kr[j].y + qq.z * kr[j].z + qq.w * kr[j].w;
    }
    attn[((long)bh * UU + u) * SS + s] = acc * SCALE;
  }
}

// ---------------------------------------------------------------------------
// K4: row softmax over S=4096, one block per row (720 rows), in place.
// ---------------------------------------------------------------------------
__global__ __launch_bounds__(256) void k_softmax(float* __restrict__ attn) {
  __shared__ float red[256];
  long row = blockIdx.x;
  float* a = attn + row * SS;
  float v[16];
  float mx = -INFINITY;
  #pragma unroll
  for (int j = 0; j < 16; ++j) {
    v[j] = a[j * 256 + threadIdx.x];
    mx = fmaxf(mx, v[j]);
  }
  red[threadIdx.x] = mx;
  __syncthreads();
  for (int st = 128; st; st >>= 1) {
    if (threadIdx.x < st) red[threadIdx.x] = fmaxf(red[threadIdx.x], red[threadIdx.x + st]);
    __syncthreads();
  }
  mx = red[0];
  __syncthreads();
  float sm = 0.f;
  #pragma unroll
  for (int j = 0; j < 16; ++j) {
    v[j] = __expf(v[j] - mx);
    sm += v[j];
  }
  red[threadIdx.x] = sm;
  __syncthreads();
  for (int st = 128; st; st >>= 1) {
    if (threadIdx.x < st) red[threadIdx.x] += red[threadIdx.x + st];
    __syncthreads();
  }
  float inv = 1.0f / red[0];
  #pragma unroll
  for (int j = 0; j < 16; ++j) a[j * 256 + threadIdx.x] = v[j] * inv;
}

// ---------------------------------------------------------------------------
// K5a: chunked context partials. grid = (nch, B*H); block = 256 (4 waves).
// All 45 u-accumulators in registers (lane = d); attn chunk staged transposed
// in LDS (row stride 52). V and attn each read once from HBM. Partials -> ws.
// ---------------------------------------------------------------------------
__global__ __launch_bounds__(256) void k_context_part(
    const float* __restrict__ attn, const float* __restrict__ v,
    float* __restrict__ part, int nch) {
  __shared__ float smem[4 * UU * DD];   // 11520 floats; staging uses 128*52
  int ch = blockIdx.x, bh = blockIdx.y;
  int b = bh >> 3, h = bh & 7;
  int tid = threadIdx.x;
  int ln = tid & 63, w = tid >> 6;
  int chunk = SS / nch;
  int s0 = ch * chunk;
  int nsub = chunk >> 7;                // 128-s sub-tiles

  float acc[UU];
  #pragma unroll
  for (int u = 0; u < UU; ++u) acc[u] = 0.f;

  const float* vb = v + (long)b * SS * HH * DD + h * DD + ln;

  for (int sub = 0; sub < nsub; ++sub) {
    int sb = s0 + (sub << 7);
    __syncthreads();                    // protect previous sub-tile reads
    for (int i = tid; i < UU * 128; i += 256) {
      int u = i >> 7, si = i & 127;
      smem[si * 52 + u] = attn[((long)bh * UU + u) * SS + sb + si];
    }
    __syncthreads();
    #pragma unroll 2
    for (int j = 0; j < 32; ++j) {
      int sl = (j << 2) + w;            // 4 waves cover 128 s
      float vd = vb[(long)(sb + sl) * (HH * DD)];
      const float* ar = smem + sl * 52;
      #pragma unroll
      for (int g = 0; g < 11; ++g) {
        float4 aa = *(const float4*)(ar + g * 4);
        acc[g * 4 + 0] += aa.x * vd;
        acc[g * 4 + 1] += aa.y * vd;
        acc[g * 4 + 2] += aa.z * vd;
        acc[g * 4 + 3] += aa.w * vd;
      }
      acc[44] += ar[44] * vd;
    }
  }

  __syncthreads();
  #pragma unroll
  for (int u = 0; u < UU; ++u) smem[(w * UU + u) * DD + ln] = acc[u];
  __syncthreads();
  long base = ((long)bh * nch + ch) * (UU * DD);
  for (int i = tid; i < UU * DD; i += 256)
    part[base + i] = smem[i] + smem[UU * DD + i] + smem[2 * UU * DD + i] + smem[3 * UU * DD + i];
}

// K5b: sum partials over chunks. 46080 outputs.
__global__ __launch_bounds__(256) void k_context_reduce(
    const float* __restrict__ part, float* __restrict__ ctx, int nch) {
  int g = blockIdx.x * 256 + threadIdx.x;     // < B*H*U*D = 46080
  int bh = g / (UU * DD);
  int r  = g - bh * (UU * DD);
  float s = 0.f;
  for (int ch = 0; ch < nch; ++ch)
    s += part[((long)bh * nch + ch) * (UU * DD) + r];
  ctx[g] = s;
}

// Fallback (row-per-block context) if d_ws is too small.
__global__ __launch_bounds__(256) void k_context_fb(
    const float* __restrict__ attn, const float* __restrict__ v,
    float* __restrict__ ctx) {
  __shared__ float red[4][DD];
  int row = blockIdx.x;
  int bh = row / UU;
  int b = bh >> 3, h = bh & 7;
  int lane = threadIdx.x & 63;
  int grp = threadIdx.x >> 6;
  const float* a = attn + (long)row * SS;
  float acc = 0.f;
  for (int s = grp; s < SS; s += 4)
    acc += a[s] * v[(((long)b * SS + s) * HH + h) * DD + lane];
  red[grp][lane] = acc;
  __syncthreads();
  if (grp == 0)
    ctx[(long)row * DD + lane] = red[0][lane] + red[1][lane] + red[2][lane] + red[3][lane];
}

extern "C" void kernel_launch(void* const* d_in, const int* in_sizes, int n_in,
                              void* d_out, int out_size, void* d_ws, size_t ws_size,
                              hipStream_t stream) {
  const float* q   = (const float*)d_in[0];
  const float* k   = (const float*)d_in[1];
  const float* v   = (const float*)d_in[2];
  const int*   idx = (const int*)d_in[3];

  float* out  = (float*)d_out;
  float* ctx  = out;                           // B*H*U*D = 46080 floats
  float* attn = out + (long)BB * HH * UU * DD; // B*H*U*S floats

  // Scratch overlays on d_out (safe via stream ordering):
  //  - M lives at start of attn region (consumed by K2 before K3 overwrites)
  //  - Mtop lives at start of ctx region (consumed by K3 before K5 overwrites)
  float* M    = attn;
  int*   Mtop = (int*)ctx;

  k_compute_M<<<BB * HH * LL / 16, 256, 0, stream>>>(q, k, idx, M);
  k_topk<<<BB * HH, 256, 0, stream>>>(M, Mtop);
  k_scores<<<dim3(SS / 256, BB * HH), 256, 0, stream>>>(q, k, Mtop, attn);
  k_softmax<<<BB * HH * UU, 256, 0, stream>>>(attn);

  size_t per_chunk = (size_t)BB * HH * UU * DD * sizeof(float);  // 184320 B
  int nch = 0;
  for (int c = 32; c >= 1; c >>= 1)
    if (ws_size >= per_chunk * (size_t)c) { nch = c; break; }
  if (nch) {
    k_context_part<<<dim3(nch, BB * HH), 256, 0, stream>>>(attn, v, (float*)d_ws, nch);
    k_context_reduce<<<(BB * HH * UU * DD) / 256, 256, 0, stream>>>((const float*)d_ws, ctx, nch);
  } else {
    k_context_fb<<<BB * HH * UU, 256, 0, stream>>>(attn, v, ctx);
  }
}